// Round 2
// baseline (310.417 us; speedup 1.0000x reference)
//
#include <hip/hip_runtime.h>
#include <math.h>

#define BB 32
#define SS 2048
#define EE 6144

// ---------------- stats of original x (ddof=1) + copy to xbuf ----------------
__global__ __launch_bounds__(256) void k_stats0(const float* __restrict__ x,
                                                float* __restrict__ xbuf,
                                                float* __restrict__ stats) {
  int b = blockIdx.x;
  const float* row = x + b * SS;
  float s = 0.f, s2 = 0.f;
  for (int j = threadIdx.x; j < SS; j += 256) {
    float v = row[j];
    xbuf[b * SS + j] = v;
    s += v; s2 += v * v;
  }
  __shared__ float sm[8];
  for (int off = 32; off; off >>= 1) { s += __shfl_down(s, off); s2 += __shfl_down(s2, off); }
  int lane = threadIdx.x & 63, wid = threadIdx.x >> 6;
  if (lane == 0) { sm[wid] = s; sm[4 + wid] = s2; }
  __syncthreads();
  if (threadIdx.x == 0) {
    float ts = sm[0] + sm[1] + sm[2] + sm[3];
    float ts2 = sm[4] + sm[5] + sm[6] + sm[7];
    float mu = ts / SS;
    float var = (ts2 - SS * mu * mu) / (SS - 1);
    stats[b] = mu;
    stats[BB + b] = var;
  }
}

// ---------------- LayerNorm for attention (row layout out) ----------------
__global__ __launch_bounds__(256) void k_layernorm(const float* __restrict__ x,
                                                   const float* __restrict__ g,
                                                   const float* __restrict__ be,
                                                   float* __restrict__ u) {
  int b = blockIdx.x;
  const float* row = x + b * SS;
  float s = 0.f, s2 = 0.f;
  for (int j = threadIdx.x; j < SS; j += 256) { float v = row[j]; s += v; s2 += v * v; }
  __shared__ float sm[8];
  __shared__ float smu, srs;
  for (int off = 32; off; off >>= 1) { s += __shfl_down(s, off); s2 += __shfl_down(s2, off); }
  int lane = threadIdx.x & 63, wid = threadIdx.x >> 6;
  if (lane == 0) { sm[wid] = s; sm[4 + wid] = s2; }
  __syncthreads();
  if (threadIdx.x == 0) {
    float ts = sm[0] + sm[1] + sm[2] + sm[3];
    float ts2 = sm[4] + sm[5] + sm[6] + sm[7];
    float mu = ts / SS;
    float var = ts2 / SS - mu * mu;
    smu = mu;
    srs = rsqrtf(var + 1e-5f);
  }
  __syncthreads();
  float mu = smu, rs = srs;
  for (int j = threadIdx.x; j < SS; j += 256) {
    float v = row[j];
    u[b * SS + j] = (v - mu) * rs * g[j] + be[j];
  }
}

// ---------------- LayerNorm writing q-layout A_q[k/4][32][4] for MLP GEMM ----------------
__global__ __launch_bounds__(256) void k_ln_q(const float* __restrict__ x,
                                              const float* __restrict__ g,
                                              const float* __restrict__ be,
                                              float* __restrict__ Aq) {
  int b = blockIdx.x;
  const float* row = x + b * SS;
  float s = 0.f, s2 = 0.f;
  for (int j = threadIdx.x; j < SS; j += 256) { float v = row[j]; s += v; s2 += v * v; }
  __shared__ float sm[8];
  __shared__ float smu, srs;
  for (int off = 32; off; off >>= 1) { s += __shfl_down(s, off); s2 += __shfl_down(s2, off); }
  int lane = threadIdx.x & 63, wid = threadIdx.x >> 6;
  if (lane == 0) { sm[wid] = s; sm[4 + wid] = s2; }
  __syncthreads();
  if (threadIdx.x == 0) {
    float ts = sm[0] + sm[1] + sm[2] + sm[3];
    float ts2 = sm[4] + sm[5] + sm[6] + sm[7];
    float mu = ts / SS;
    float var = ts2 / SS - mu * mu;
    smu = mu;
    srs = rsqrtf(var + 1e-5f);
  }
  __syncthreads();
  float mu = smu, rs = srs;
  for (int kq = threadIdx.x; kq < SS / 4; kq += 256) {
    float4 v  = *reinterpret_cast<const float4*>(row + (kq << 2));
    float4 gg = *reinterpret_cast<const float4*>(g + (kq << 2));
    float4 bb = *reinterpret_cast<const float4*>(be + (kq << 2));
    float4 o;
    o.x = (v.x - mu) * rs * gg.x + bb.x;
    o.y = (v.y - mu) * rs * gg.y + bb.y;
    o.z = (v.z - mu) * rs * gg.z + bb.z;
    o.w = (v.w - mu) * rs * gg.w + bb.w;
    *reinterpret_cast<float4*>(Aq + (size_t)kq * 128 + (b << 2)) = o;
  }
}

// ---------------- attention core (head_dim=1), j-split x4 ----------------
__global__ __launch_bounds__(256) void k_attn(const float* __restrict__ u,
                                              float* __restrict__ xbuf,
                                              const float* __restrict__ ipw,
                                              const float* __restrict__ ipb,
                                              const float* __restrict__ owp,
                                              const float* __restrict__ obp) {
  int b = blockIdx.y;
  __shared__ float2 kv[SS];
  __shared__ float red[8];
  __shared__ float skmax, skmin;
  __shared__ float ssum[3][64], tsum[3][64];
  float wq = ipw[0], wk = ipw[1], wv = ipw[2];
  float bq = ipb[0], bk = ipb[1], bv = ipb[2];
  const float* urow = u + b * SS;
  float kmax = -1e30f, kmin = 1e30f;
  for (int j = threadIdx.x; j < SS; j += 256) {
    float uu = urow[j];
    float kj = fmaf(uu, wk, bk);
    float vj = fmaf(uu, wv, bv);
    kv[j] = make_float2(kj, vj);
    kmax = fmaxf(kmax, kj);
    kmin = fminf(kmin, kj);
  }
  for (int off = 32; off; off >>= 1) {
    kmax = fmaxf(kmax, __shfl_down(kmax, off));
    kmin = fminf(kmin, __shfl_down(kmin, off));
  }
  int lane = threadIdx.x & 63, wid = threadIdx.x >> 6;
  if (lane == 0) { red[wid] = kmax; red[4 + wid] = kmin; }
  __syncthreads();
  if (threadIdx.x == 0) {
    skmax = fmaxf(fmaxf(red[0], red[1]), fmaxf(red[2], red[3]));
    skmin = fminf(fminf(red[4], red[5]), fminf(red[6], red[7]));
  }
  __syncthreads();
  kmax = skmax; kmin = skmin;
  int il = threadIdx.x & 63;
  int jq = threadIdx.x >> 6;
  int i = blockIdx.x * 64 + il;
  float q = fmaf(urow[i], wq, bq);
  float m = fmaxf(q * kmax, q * kmin);
  float s = 0.f, t = 0.f;
  int j0 = jq * 512;
#pragma unroll 4
  for (int j = j0; j < j0 + 512; j++) {
    float2 c = kv[j];
    float e = __expf(fmaf(q, c.x, -m));
    s += e;
    t = fmaf(e, c.y, t);
  }
  if (jq) { ssum[jq - 1][il] = s; tsum[jq - 1][il] = t; }
  __syncthreads();
  if (jq == 0) {
    s += ssum[0][il] + ssum[1][il] + ssum[2][il];
    t += tsum[0][il] + tsum[1][il] + tsum[2][il];
    float o = t / s;
    xbuf[b * SS + i] += fmaf(o, owp[0], obp[0]);
  }
}

// ---------------- streaming skinny GEMM ----------------
// A_q: [K/4][32][4]; W: [N][K]; part: [ksplit][N/4][32][4]
// grid: (N/64, K/256); block 256 (4 waves).
// lane&31 = batch b; lane>>5 = half; wave w: rows e0 = bx*64 + w*16 + half*8 .. +7.
// Per 4k step: 1 A dwordx4 (coalesced across 32 lanes) + 8 W dwordx4
// (uniform per half-wave, coalesced) + 32 fma. No LDS, no cross-lane reduce.
#define ROW_FMA(ACC, WREG) \
  ACC = fmaf(a.x, WREG.x, ACC); ACC = fmaf(a.y, WREG.y, ACC); \
  ACC = fmaf(a.z, WREG.z, ACC); ACC = fmaf(a.w, WREG.w, ACC);

__global__ __launch_bounds__(256, 3) void k_gemm_stream(const float* __restrict__ Aq,
                                                        const float* __restrict__ W,
                                                        float* __restrict__ part,
                                                        int K, int N) {
  int tid = threadIdx.x;
  int wave = tid >> 6, lane = tid & 63, b = lane & 31, h = lane >> 5;
  int e0 = (blockIdx.x << 6) + (wave << 4) + (h << 3);
  int k0 = blockIdx.y << 8;  // KCH = 256
  const float* ap = Aq + (size_t)(k0 >> 2) * 128 + (b << 2);
  const float* w0p = W + (size_t)(e0 + 0) * K + k0;
  const float* w1p = W + (size_t)(e0 + 1) * K + k0;
  const float* w2p = W + (size_t)(e0 + 2) * K + k0;
  const float* w3p = W + (size_t)(e0 + 3) * K + k0;
  const float* w4p = W + (size_t)(e0 + 4) * K + k0;
  const float* w5p = W + (size_t)(e0 + 5) * K + k0;
  const float* w6p = W + (size_t)(e0 + 6) * K + k0;
  const float* w7p = W + (size_t)(e0 + 7) * K + k0;
  float4 accA = make_float4(0.f, 0.f, 0.f, 0.f);
  float4 accB = make_float4(0.f, 0.f, 0.f, 0.f);
  for (int kk = 0; kk < 256; kk += 32) {
#pragma unroll
    for (int i = 0; i < 8; i++) {
      float4 a  = *reinterpret_cast<const float4*>(ap + i * 128);
      float4 w0 = *reinterpret_cast<const float4*>(w0p + i * 4);
      float4 w1 = *reinterpret_cast<const float4*>(w1p + i * 4);
      float4 w2 = *reinterpret_cast<const float4*>(w2p + i * 4);
      float4 w3 = *reinterpret_cast<const float4*>(w3p + i * 4);
      float4 w4 = *reinterpret_cast<const float4*>(w4p + i * 4);
      float4 w5 = *reinterpret_cast<const float4*>(w5p + i * 4);
      float4 w6 = *reinterpret_cast<const float4*>(w6p + i * 4);
      float4 w7 = *reinterpret_cast<const float4*>(w7p + i * 4);
      ROW_FMA(accA.x, w0) ROW_FMA(accA.y, w1) ROW_FMA(accA.z, w2) ROW_FMA(accA.w, w3)
      ROW_FMA(accB.x, w4) ROW_FMA(accB.y, w5) ROW_FMA(accB.z, w6) ROW_FMA(accB.w, w7)
    }
    ap += 1024;
    w0p += 32; w1p += 32; w2p += 32; w3p += 32;
    w4p += 32; w5p += 32; w6p += 32; w7p += 32;
  }
  size_t obase = (size_t)blockIdx.y * ((size_t)N * 32) + (size_t)(e0 >> 2) * 128 + (b << 2);
  *reinterpret_cast<float4*>(part + obase) = accA;
  *reinterpret_cast<float4*>(part + obase + 128) = accB;
}

// ---------------- reduce gemm1 partials (ks=8): bias + leakyrelu -> h_q (q-layout) ----------------
__global__ __launch_bounds__(256) void k_reduce1(const float* __restrict__ part,
                                                 const float* __restrict__ b1,
                                                 float* __restrict__ hq) {
  int idx = blockIdx.x * 256 + threadIdx.x;  // < 196608
  float s = 0.f;
#pragma unroll
  for (int ks = 0; ks < 8; ks++) s += part[(size_t)ks * (BB * EE) + idx];
  int e = ((idx >> 7) << 2) | (idx & 3);
  s += b1[e];
  hq[idx] = s >= 0.f ? s : 0.5f * s;
}

// ---------------- reduce gemm2 partials (ks=24): bias + residual -> xbuf[b][s] ----------------
// block handles 64 s-columns x 32 b; LDS transpose for coalesced xbuf writes.
__global__ __launch_bounds__(256) void k_reduce2(const float* __restrict__ part,
                                                 const float* __restrict__ b2,
                                                 float* __restrict__ xbuf) {
  __shared__ float ls[32][65];
  int s0 = blockIdx.x * 64;
  int base = (s0 >> 2) * 128;
  int t = threadIdx.x;
#pragma unroll
  for (int i = 0; i < 8; i++) {
    int idx = t + 256 * i;  // 0..2047 within tile
    float s = 0.f;
#pragma unroll
    for (int ks = 0; ks < 24; ks++) s += part[(size_t)ks * (BB * SS) + base + idx];
    int sq = idx >> 7, bb = (idx >> 2) & 31, j = idx & 3;
    ls[bb][(sq << 2) | j] = s;
  }
  __syncthreads();
  int r = t >> 3, sc = (t & 7) * 8;
  float* xp = xbuf + (size_t)r * SS + s0 + sc;
  const float* bp = b2 + s0 + sc;
#pragma unroll
  for (int q = 0; q < 8; q++) xp[q] += ls[r][sc + q] + bp[q];
}

// ---------------- final renorm to original mean/var ----------------
__global__ __launch_bounds__(256) void k_final(const float* __restrict__ xbuf,
                                               const float* __restrict__ stats,
                                               float* __restrict__ out) {
  int b = blockIdx.x;
  const float* row = xbuf + b * SS;
  float s = 0.f, s2 = 0.f;
  for (int j = threadIdx.x; j < SS; j += 256) { float v = row[j]; s += v; s2 += v * v; }
  __shared__ float sm[8];
  __shared__ float smu, srs;
  for (int off = 32; off; off >>= 1) { s += __shfl_down(s, off); s2 += __shfl_down(s2, off); }
  int lane = threadIdx.x & 63, wid = threadIdx.x >> 6;
  if (lane == 0) { sm[wid] = s; sm[4 + wid] = s2; }
  __syncthreads();
  if (threadIdx.x == 0) {
    float ts = sm[0] + sm[1] + sm[2] + sm[3];
    float ts2 = sm[4] + sm[5] + sm[6] + sm[7];
    float mu = ts / SS;
    float var = (ts2 - SS * mu * mu) / (SS - 1);
    smu = mu;
    srs = rsqrtf(var + 2.220446049250313e-16f);
  }
  __syncthreads();
  float mu = smu, rs = srs;
  float scale = sqrtf(stats[BB + b] + 2.220446049250313e-16f);
  float mean0 = stats[b];
  for (int j = threadIdx.x; j < SS; j += 256) {
    out[b * SS + j] = (row[j] - mu) * rs * scale + mean0;
  }
}

extern "C" void kernel_launch(void* const* d_in, const int* in_sizes, int n_in,
                              void* d_out, int out_size, void* d_ws, size_t ws_size,
                              hipStream_t stream) {
  const float* x         = (const float*)d_in[0];
  const float* attn_ln_g = (const float*)d_in[1];
  const float* attn_ln_b = (const float*)d_in[2];
  const float* ipw       = (const float*)d_in[3];
  const float* ipb       = (const float*)d_in[4];
  const float* out_w     = (const float*)d_in[5];
  const float* out_b     = (const float*)d_in[6];
  const float* mlp_ln_g  = (const float*)d_in[7];
  const float* mlp_ln_b  = (const float*)d_in[8];
  const float* W1        = (const float*)d_in[9];
  const float* b1        = (const float*)d_in[10];
  const float* W2        = (const float*)d_in[11];
  const float* b2        = (const float*)d_in[12];

  float* ws    = (float*)d_ws;
  float* xbuf  = ws;                        // 65536
  float* uq    = xbuf + BB * SS;            // 65536 (shared: u for attn, A_q for MLP)
  float* hq    = uq + BB * SS;              // 196608
  float* part  = hq + BB * EE;              // 1572864 (8*196608 == 24*65536)
  float* stats = part + 8 * BB * EE;        // 64

  k_stats0<<<BB, 256, 0, stream>>>(x, xbuf, stats);

  for (int l = 0; l < 2; l++) {
    // ---- attention block ----
    k_layernorm<<<BB, 256, 0, stream>>>(xbuf, attn_ln_g + l * SS, attn_ln_b + l * SS, uq);
    k_attn<<<dim3(SS / 64, BB), 256, 0, stream>>>(uq, xbuf, ipw + l * 3, ipb + l * 3,
                                                  out_w + l, out_b + l);
    // ---- MLP block ----
    k_ln_q<<<BB, 256, 0, stream>>>(xbuf, mlp_ln_g + l * SS, mlp_ln_b + l * SS, uq);
    k_gemm_stream<<<dim3(EE / 64, 8), 256, 0, stream>>>(uq, W1 + (size_t)l * EE * SS, part,
                                                        SS, EE);
    k_reduce1<<<BB * EE / 256, 256, 0, stream>>>(part, b1 + (size_t)l * EE, hq);
    k_gemm_stream<<<dim3(SS / 64, 24), 256, 0, stream>>>(hq, W2 + (size_t)l * SS * EE, part,
                                                         EE, SS);
    k_reduce2<<<SS / 64, 256, 0, stream>>>(part, b2 + (size_t)l * SS, xbuf);
  }

  k_final<<<BB, 256, 0, stream>>>(xbuf, stats, (float*)d_out);
}

// Round 3
// 309.927 us; speedup vs baseline: 1.0016x; 1.0016x over previous
//
#include <hip/hip_runtime.h>
#include <math.h>

#define BB 32
#define SS 2048
#define EE 6144

// ---------------- stats of original x (ddof=1) + copy to xbuf ----------------
__global__ __launch_bounds__(256) void k_stats0(const float* __restrict__ x,
                                                float* __restrict__ xbuf,
                                                float* __restrict__ stats) {
  int b = blockIdx.x;
  const float* row = x + b * SS;
  float s = 0.f, s2 = 0.f;
  for (int j = threadIdx.x; j < SS; j += 256) {
    float v = row[j];
    xbuf[b * SS + j] = v;
    s += v; s2 += v * v;
  }
  __shared__ float sm[8];
  for (int off = 32; off; off >>= 1) { s += __shfl_down(s, off); s2 += __shfl_down(s2, off); }
  int lane = threadIdx.x & 63, wid = threadIdx.x >> 6;
  if (lane == 0) { sm[wid] = s; sm[4 + wid] = s2; }
  __syncthreads();
  if (threadIdx.x == 0) {
    float ts = sm[0] + sm[1] + sm[2] + sm[3];
    float ts2 = sm[4] + sm[5] + sm[6] + sm[7];
    float mu = ts / SS;
    float var = (ts2 - SS * mu * mu) / (SS - 1);
    stats[b] = mu;
    stats[BB + b] = var;
  }
}

// ---------------- LayerNorm for attention (row layout out) ----------------
__global__ __launch_bounds__(256) void k_layernorm(const float* __restrict__ x,
                                                   const float* __restrict__ g,
                                                   const float* __restrict__ be,
                                                   float* __restrict__ u) {
  int b = blockIdx.x;
  const float* row = x + b * SS;
  float s = 0.f, s2 = 0.f;
  for (int j = threadIdx.x; j < SS; j += 256) { float v = row[j]; s += v; s2 += v * v; }
  __shared__ float sm[8];
  __shared__ float smu, srs;
  for (int off = 32; off; off >>= 1) { s += __shfl_down(s, off); s2 += __shfl_down(s2, off); }
  int lane = threadIdx.x & 63, wid = threadIdx.x >> 6;
  if (lane == 0) { sm[wid] = s; sm[4 + wid] = s2; }
  __syncthreads();
  if (threadIdx.x == 0) {
    float ts = sm[0] + sm[1] + sm[2] + sm[3];
    float ts2 = sm[4] + sm[5] + sm[6] + sm[7];
    float mu = ts / SS;
    float var = ts2 / SS - mu * mu;
    smu = mu;
    srs = rsqrtf(var + 1e-5f);
  }
  __syncthreads();
  float mu = smu, rs = srs;
  for (int j = threadIdx.x; j < SS; j += 256) {
    float v = row[j];
    u[b * SS + j] = (v - mu) * rs * g[j] + be[j];
  }
}

// ---------------- LayerNorm writing q-layout A_q[k/4][32][4] for MLP GEMM ----------------
__global__ __launch_bounds__(256) void k_ln_q(const float* __restrict__ x,
                                              const float* __restrict__ g,
                                              const float* __restrict__ be,
                                              float* __restrict__ Aq) {
  int b = blockIdx.x;
  const float* row = x + b * SS;
  float s = 0.f, s2 = 0.f;
  for (int j = threadIdx.x; j < SS; j += 256) { float v = row[j]; s += v; s2 += v * v; }
  __shared__ float sm[8];
  __shared__ float smu, srs;
  for (int off = 32; off; off >>= 1) { s += __shfl_down(s, off); s2 += __shfl_down(s2, off); }
  int lane = threadIdx.x & 63, wid = threadIdx.x >> 6;
  if (lane == 0) { sm[wid] = s; sm[4 + wid] = s2; }
  __syncthreads();
  if (threadIdx.x == 0) {
    float ts = sm[0] + sm[1] + sm[2] + sm[3];
    float ts2 = sm[4] + sm[5] + sm[6] + sm[7];
    float mu = ts / SS;
    float var = ts2 / SS - mu * mu;
    smu = mu;
    srs = rsqrtf(var + 1e-5f);
  }
  __syncthreads();
  float mu = smu, rs = srs;
  for (int kq = threadIdx.x; kq < SS / 4; kq += 256) {
    float4 v  = *reinterpret_cast<const float4*>(row + (kq << 2));
    float4 gg = *reinterpret_cast<const float4*>(g + (kq << 2));
    float4 bb = *reinterpret_cast<const float4*>(be + (kq << 2));
    float4 o;
    o.x = (v.x - mu) * rs * gg.x + bb.x;
    o.y = (v.y - mu) * rs * gg.y + bb.y;
    o.z = (v.z - mu) * rs * gg.z + bb.z;
    o.w = (v.w - mu) * rs * gg.w + bb.w;
    *reinterpret_cast<float4*>(Aq + (size_t)kq * 128 + (b << 2)) = o;
  }
}

// ---------------- attention core (head_dim=1), j-split x4 ----------------
__global__ __launch_bounds__(256) void k_attn(const float* __restrict__ u,
                                              float* __restrict__ xbuf,
                                              const float* __restrict__ ipw,
                                              const float* __restrict__ ipb,
                                              const float* __restrict__ owp,
                                              const float* __restrict__ obp) {
  int b = blockIdx.y;
  __shared__ float2 kv[SS];
  __shared__ float red[8];
  __shared__ float skmax, skmin;
  __shared__ float ssum[3][64], tsum[3][64];
  float wq = ipw[0], wk = ipw[1], wv = ipw[2];
  float bq = ipb[0], bk = ipb[1], bv = ipb[2];
  const float* urow = u + b * SS;
  float kmax = -1e30f, kmin = 1e30f;
  for (int j = threadIdx.x; j < SS; j += 256) {
    float uu = urow[j];
    float kj = fmaf(uu, wk, bk);
    float vj = fmaf(uu, wv, bv);
    kv[j] = make_float2(kj, vj);
    kmax = fmaxf(kmax, kj);
    kmin = fminf(kmin, kj);
  }
  for (int off = 32; off; off >>= 1) {
    kmax = fmaxf(kmax, __shfl_down(kmax, off));
    kmin = fminf(kmin, __shfl_down(kmin, off));
  }
  int lane = threadIdx.x & 63, wid = threadIdx.x >> 6;
  if (lane == 0) { red[wid] = kmax; red[4 + wid] = kmin; }
  __syncthreads();
  if (threadIdx.x == 0) {
    skmax = fmaxf(fmaxf(red[0], red[1]), fmaxf(red[2], red[3]));
    skmin = fminf(fminf(red[4], red[5]), fminf(red[6], red[7]));
  }
  __syncthreads();
  kmax = skmax; kmin = skmin;
  int il = threadIdx.x & 63;
  int jq = threadIdx.x >> 6;
  int i = blockIdx.x * 64 + il;
  float q = fmaf(urow[i], wq, bq);
  float m = fmaxf(q * kmax, q * kmin);
  float s = 0.f, t = 0.f;
  int j0 = jq * 512;
#pragma unroll 4
  for (int j = j0; j < j0 + 512; j++) {
    float2 c = kv[j];
    float e = __expf(fmaf(q, c.x, -m));
    s += e;
    t = fmaf(e, c.y, t);
  }
  if (jq) { ssum[jq - 1][il] = s; tsum[jq - 1][il] = t; }
  __syncthreads();
  if (jq == 0) {
    s += ssum[0][il] + ssum[1][il] + ssum[2][il];
    t += tsum[0][il] + tsum[1][il] + tsum[2][il];
    float o = t / s;
    xbuf[b * SS + i] += fmaf(o, owp[0], obp[0]);
  }
}

// ---------------- streaming skinny GEMM ----------------
// A_q: [K/4][32][4]; W: [N][K]; part: [ksplit][N/4][32][4]
// grid: (N/64, K/256); block 256 (4 waves).
// lane&31 = batch b; lane>>5 = half; wave w: rows e0 = bx*64 + w*16 + half*8 .. +7.
// Per 4k step: 1 A dwordx4 (coalesced across 32 lanes) + 8 W dwordx4
// (uniform per half-wave, coalesced) + 32 fma. No LDS, no cross-lane reduce.
#define ROW_FMA(ACC, WREG) \
  ACC = fmaf(a.x, WREG.x, ACC); ACC = fmaf(a.y, WREG.y, ACC); \
  ACC = fmaf(a.z, WREG.z, ACC); ACC = fmaf(a.w, WREG.w, ACC);

__global__ __launch_bounds__(256, 3) void k_gemm_stream(const float* __restrict__ Aq,
                                                        const float* __restrict__ W,
                                                        float* __restrict__ part,
                                                        int K, int N) {
  int tid = threadIdx.x;
  int wave = tid >> 6, lane = tid & 63, b = lane & 31, h = lane >> 5;
  int e0 = (blockIdx.x << 6) + (wave << 4) + (h << 3);
  int k0 = blockIdx.y << 8;  // KCH = 256
  const float* ap = Aq + (size_t)(k0 >> 2) * 128 + (b << 2);
  const float* w0p = W + (size_t)(e0 + 0) * K + k0;
  const float* w1p = W + (size_t)(e0 + 1) * K + k0;
  const float* w2p = W + (size_t)(e0 + 2) * K + k0;
  const float* w3p = W + (size_t)(e0 + 3) * K + k0;
  const float* w4p = W + (size_t)(e0 + 4) * K + k0;
  const float* w5p = W + (size_t)(e0 + 5) * K + k0;
  const float* w6p = W + (size_t)(e0 + 6) * K + k0;
  const float* w7p = W + (size_t)(e0 + 7) * K + k0;
  float4 accA = make_float4(0.f, 0.f, 0.f, 0.f);
  float4 accB = make_float4(0.f, 0.f, 0.f, 0.f);
  for (int kk = 0; kk < 256; kk += 32) {
#pragma unroll
    for (int i = 0; i < 8; i++) {
      float4 a  = *reinterpret_cast<const float4*>(ap + i * 128);
      float4 w0 = *reinterpret_cast<const float4*>(w0p + i * 4);
      float4 w1 = *reinterpret_cast<const float4*>(w1p + i * 4);
      float4 w2 = *reinterpret_cast<const float4*>(w2p + i * 4);
      float4 w3 = *reinterpret_cast<const float4*>(w3p + i * 4);
      float4 w4 = *reinterpret_cast<const float4*>(w4p + i * 4);
      float4 w5 = *reinterpret_cast<const float4*>(w5p + i * 4);
      float4 w6 = *reinterpret_cast<const float4*>(w6p + i * 4);
      float4 w7 = *reinterpret_cast<const float4*>(w7p + i * 4);
      ROW_FMA(accA.x, w0) ROW_FMA(accA.y, w1) ROW_FMA(accA.z, w2) ROW_FMA(accA.w, w3)
      ROW_FMA(accB.x, w4) ROW_FMA(accB.y, w5) ROW_FMA(accB.z, w6) ROW_FMA(accB.w, w7)
    }
    ap += 1024;
    w0p += 32; w1p += 32; w2p += 32; w3p += 32;
    w4p += 32; w5p += 32; w6p += 32; w7p += 32;
  }
  size_t obase = (size_t)blockIdx.y * ((size_t)N * 32) + (size_t)(e0 >> 2) * 128 + (b << 2);
  *reinterpret_cast<float4*>(part + obase) = accA;
  *reinterpret_cast<float4*>(part + obase + 128) = accB;
}

// ---------------- reduce gemm1 partials (ks=8): bias + leakyrelu -> h_q (q-layout) ----------------
__global__ __launch_bounds__(256) void k_reduce1(const float* __restrict__ part,
                                                 const float* __restrict__ b1,
                                                 float* __restrict__ hq) {
  int idx = blockIdx.x * 256 + threadIdx.x;  // < 196608
  float s = 0.f;
#pragma unroll
  for (int ks = 0; ks < 8; ks++) s += part[(size_t)ks * (BB * EE) + idx];
  int e = ((idx >> 7) << 2) | (idx & 3);
  s += b1[e];
  hq[idx] = s >= 0.f ? s : 0.5f * s;
}

// ---------------- reduce gemm2 partials (ks=24): bias + residual -> xbuf[b][s] ----------------
// block handles 64 s-columns x 32 b; LDS transpose for coalesced xbuf writes.
__global__ __launch_bounds__(256) void k_reduce2(const float* __restrict__ part,
                                                 const float* __restrict__ b2,
                                                 float* __restrict__ xbuf) {
  __shared__ float ls[32][65];
  int s0 = blockIdx.x * 64;
  int base = (s0 >> 2) * 128;
  int t = threadIdx.x;
#pragma unroll
  for (int i = 0; i < 8; i++) {
    int idx = t + 256 * i;  // 0..2047 within tile
    float s = 0.f;
#pragma unroll
    for (int ks = 0; ks < 24; ks++) s += part[(size_t)ks * (BB * SS) + base + idx];
    int sq = idx >> 7, bb = (idx >> 2) & 31, j = idx & 3;
    ls[bb][(sq << 2) | j] = s;
  }
  __syncthreads();
  int r = t >> 3, sc = (t & 7) * 8;
  float* xp = xbuf + (size_t)r * SS + s0 + sc;
  const float* bp = b2 + s0 + sc;
#pragma unroll
  for (int q = 0; q < 8; q++) xp[q] += ls[r][sc + q] + bp[q];
}

// ---------------- final renorm to original mean/var ----------------
__global__ __launch_bounds__(256) void k_final(const float* __restrict__ xbuf,
                                               const float* __restrict__ stats,
                                               float* __restrict__ out) {
  int b = blockIdx.x;
  const float* row = xbuf + b * SS;
  float s = 0.f, s2 = 0.f;
  for (int j = threadIdx.x; j < SS; j += 256) { float v = row[j]; s += v; s2 += v * v; }
  __shared__ float sm[8];
  __shared__ float smu, srs;
  for (int off = 32; off; off >>= 1) { s += __shfl_down(s, off); s2 += __shfl_down(s2, off); }
  int lane = threadIdx.x & 63, wid = threadIdx.x >> 6;
  if (lane == 0) { sm[wid] = s; sm[4 + wid] = s2; }
  __syncthreads();
  if (threadIdx.x == 0) {
    float ts = sm[0] + sm[1] + sm[2] + sm[3];
    float ts2 = sm[4] + sm[5] + sm[6] + sm[7];
    float mu = ts / SS;
    float var = (ts2 - SS * mu * mu) / (SS - 1);
    smu = mu;
    srs = rsqrtf(var + 2.220446049250313e-16f);
  }
  __syncthreads();
  float mu = smu, rs = srs;
  float scale = sqrtf(stats[BB + b] + 2.220446049250313e-16f);
  float mean0 = stats[b];
  for (int j = threadIdx.x; j < SS; j += 256) {
    out[b * SS + j] = (row[j] - mu) * rs * scale + mean0;
  }
}

extern "C" void kernel_launch(void* const* d_in, const int* in_sizes, int n_in,
                              void* d_out, int out_size, void* d_ws, size_t ws_size,
                              hipStream_t stream) {
  const float* x         = (const float*)d_in[0];
  const float* attn_ln_g = (const float*)d_in[1];
  const float* attn_ln_b = (const float*)d_in[2];
  const float* ipw       = (const float*)d_in[3];
  const float* ipb       = (const float*)d_in[4];
  const float* out_w     = (const float*)d_in[5];
  const float* out_b     = (const float*)d_in[6];
  const float* mlp_ln_g  = (const float*)d_in[7];
  const float* mlp_ln_b  = (const float*)d_in[8];
  const float* W1        = (const float*)d_in[9];
  const float* b1        = (const float*)d_in[10];
  const float* W2        = (const float*)d_in[11];
  const float* b2        = (const float*)d_in[12];

  float* ws    = (float*)d_ws;
  float* xbuf  = ws;                        // 65536
  float* uq    = xbuf + BB * SS;            // 65536 (shared: u for attn, A_q for MLP)
  float* hq    = uq + BB * SS;              // 196608
  float* part  = hq + BB * EE;              // 1572864 (8*196608 == 24*65536)
  float* stats = part + 8 * BB * EE;        // 64

  k_stats0<<<BB, 256, 0, stream>>>(x, xbuf, stats);

  for (int l = 0; l < 2; l++) {
    // ---- attention block ----
    k_layernorm<<<BB, 256, 0, stream>>>(xbuf, attn_ln_g + l * SS, attn_ln_b + l * SS, uq);
    k_attn<<<dim3(SS / 64, BB), 256, 0, stream>>>(uq, xbuf, ipw + l * 3, ipb + l * 3,
                                                  out_w + l, out_b + l);
    // ---- MLP block ----
    k_ln_q<<<BB, 256, 0, stream>>>(xbuf, mlp_ln_g + l * SS, mlp_ln_b + l * SS, uq);
    k_gemm_stream<<<dim3(EE / 64, 8), 256, 0, stream>>>(uq, W1 + (size_t)l * EE * SS, part,
                                                        SS, EE);
    k_reduce1<<<BB * EE / 256, 256, 0, stream>>>(part, b1 + (size_t)l * EE, hq);
    k_gemm_stream<<<dim3(SS / 64, 24), 256, 0, stream>>>(hq, W2 + (size_t)l * SS * EE, part,
                                                         EE, SS);
    k_reduce2<<<SS / 64, 256, 0, stream>>>(part, b2 + (size_t)l * SS, xbuf);
  }

  k_final<<<BB, 256, 0, stream>>>(xbuf, stats, (float*)d_out);
}

// Round 4
// 220.388 us; speedup vs baseline: 1.4085x; 1.4063x over previous
//
#include <hip/hip_runtime.h>
#include <math.h>

#define BB 32
#define SS 2048
#define EE 6144
#define KC 256   // K-chunk per block
#define KT 64    // k per LDS tile
#define NT (KC / KT)

#define GLOAD_LDS16(gsrc, ldst)                                                 \
  __builtin_amdgcn_global_load_lds(                                             \
      (const __attribute__((address_space(1))) void*)(gsrc),                    \
      (__attribute__((address_space(3))) void*)(ldst), 16, 0, 0)

// ---------------- stats of original x (ddof=1) + copy to xbuf ----------------
__global__ __launch_bounds__(256) void k_stats0(const float* __restrict__ x,
                                                float* __restrict__ xbuf,
                                                float* __restrict__ stats) {
  int b = blockIdx.x;
  const float* row = x + b * SS;
  float s = 0.f, s2 = 0.f;
  for (int j = threadIdx.x; j < SS; j += 256) {
    float v = row[j];
    xbuf[b * SS + j] = v;
    s += v; s2 += v * v;
  }
  __shared__ float sm[8];
  for (int off = 32; off; off >>= 1) { s += __shfl_down(s, off); s2 += __shfl_down(s2, off); }
  int lane = threadIdx.x & 63, wid = threadIdx.x >> 6;
  if (lane == 0) { sm[wid] = s; sm[4 + wid] = s2; }
  __syncthreads();
  if (threadIdx.x == 0) {
    float ts = sm[0] + sm[1] + sm[2] + sm[3];
    float ts2 = sm[4] + sm[5] + sm[6] + sm[7];
    float mu = ts / SS;
    float var = (ts2 - SS * mu * mu) / (SS - 1);
    stats[b] = mu;
    stats[BB + b] = var;
  }
}

// ---------------- LayerNorm for attention (row layout out) ----------------
__global__ __launch_bounds__(256) void k_layernorm(const float* __restrict__ x,
                                                   const float* __restrict__ g,
                                                   const float* __restrict__ be,
                                                   float* __restrict__ u) {
  int b = blockIdx.x;
  const float* row = x + b * SS;
  float s = 0.f, s2 = 0.f;
  for (int j = threadIdx.x; j < SS; j += 256) { float v = row[j]; s += v; s2 += v * v; }
  __shared__ float sm[8];
  __shared__ float smu, srs;
  for (int off = 32; off; off >>= 1) { s += __shfl_down(s, off); s2 += __shfl_down(s2, off); }
  int lane = threadIdx.x & 63, wid = threadIdx.x >> 6;
  if (lane == 0) { sm[wid] = s; sm[4 + wid] = s2; }
  __syncthreads();
  if (threadIdx.x == 0) {
    float ts = sm[0] + sm[1] + sm[2] + sm[3];
    float ts2 = sm[4] + sm[5] + sm[6] + sm[7];
    float mu = ts / SS;
    float var = ts2 / SS - mu * mu;
    smu = mu;
    srs = rsqrtf(var + 1e-5f);
  }
  __syncthreads();
  float mu = smu, rs = srs;
  for (int j = threadIdx.x; j < SS; j += 256) {
    float v = row[j];
    u[b * SS + j] = (v - mu) * rs * g[j] + be[j];
  }
}

// ---------------- LayerNorm writing q-layout A_q[k/4][32][4] for MLP GEMM ----------------
__global__ __launch_bounds__(256) void k_ln_q(const float* __restrict__ x,
                                              const float* __restrict__ g,
                                              const float* __restrict__ be,
                                              float* __restrict__ Aq) {
  int b = blockIdx.x;
  const float* row = x + b * SS;
  float s = 0.f, s2 = 0.f;
  for (int j = threadIdx.x; j < SS; j += 256) { float v = row[j]; s += v; s2 += v * v; }
  __shared__ float sm[8];
  __shared__ float smu, srs;
  for (int off = 32; off; off >>= 1) { s += __shfl_down(s, off); s2 += __shfl_down(s2, off); }
  int lane = threadIdx.x & 63, wid = threadIdx.x >> 6;
  if (lane == 0) { sm[wid] = s; sm[4 + wid] = s2; }
  __syncthreads();
  if (threadIdx.x == 0) {
    float ts = sm[0] + sm[1] + sm[2] + sm[3];
    float ts2 = sm[4] + sm[5] + sm[6] + sm[7];
    float mu = ts / SS;
    float var = ts2 / SS - mu * mu;
    smu = mu;
    srs = rsqrtf(var + 1e-5f);
  }
  __syncthreads();
  float mu = smu, rs = srs;
  for (int kq = threadIdx.x; kq < SS / 4; kq += 256) {
    float4 v  = *reinterpret_cast<const float4*>(row + (kq << 2));
    float4 gg = *reinterpret_cast<const float4*>(g + (kq << 2));
    float4 bb = *reinterpret_cast<const float4*>(be + (kq << 2));
    float4 o;
    o.x = (v.x - mu) * rs * gg.x + bb.x;
    o.y = (v.y - mu) * rs * gg.y + bb.y;
    o.z = (v.z - mu) * rs * gg.z + bb.z;
    o.w = (v.w - mu) * rs * gg.w + bb.w;
    *reinterpret_cast<float4*>(Aq + (size_t)kq * 128 + (b << 2)) = o;
  }
}

// ---------------- attention core (head_dim=1), j-split x4 ----------------
__global__ __launch_bounds__(256) void k_attn(const float* __restrict__ u,
                                              float* __restrict__ xbuf,
                                              const float* __restrict__ ipw,
                                              const float* __restrict__ ipb,
                                              const float* __restrict__ owp,
                                              const float* __restrict__ obp) {
  int b = blockIdx.y;
  __shared__ float2 kv[SS];
  __shared__ float red[8];
  __shared__ float skmax, skmin;
  __shared__ float ssum[3][64], tsum[3][64];
  float wq = ipw[0], wk = ipw[1], wv = ipw[2];
  float bq = ipb[0], bk = ipb[1], bv = ipb[2];
  const float* urow = u + b * SS;
  float kmax = -1e30f, kmin = 1e30f;
  for (int j = threadIdx.x; j < SS; j += 256) {
    float uu = urow[j];
    float kj = fmaf(uu, wk, bk);
    float vj = fmaf(uu, wv, bv);
    kv[j] = make_float2(kj, vj);
    kmax = fmaxf(kmax, kj);
    kmin = fminf(kmin, kj);
  }
  for (int off = 32; off; off >>= 1) {
    kmax = fmaxf(kmax, __shfl_down(kmax, off));
    kmin = fminf(kmin, __shfl_down(kmin, off));
  }
  int lane = threadIdx.x & 63, wid = threadIdx.x >> 6;
  if (lane == 0) { red[wid] = kmax; red[4 + wid] = kmin; }
  __syncthreads();
  if (threadIdx.x == 0) {
    skmax = fmaxf(fmaxf(red[0], red[1]), fmaxf(red[2], red[3]));
    skmin = fminf(fminf(red[4], red[5]), fminf(red[6], red[7]));
  }
  __syncthreads();
  kmax = skmax; kmin = skmin;
  int il = threadIdx.x & 63;
  int jq = threadIdx.x >> 6;
  int i = blockIdx.x * 64 + il;
  float q = fmaf(urow[i], wq, bq);
  float m = fmaxf(q * kmax, q * kmin);
  float s = 0.f, t = 0.f;
  int j0 = jq * 512;
#pragma unroll 4
  for (int j = j0; j < j0 + 512; j++) {
    float2 c = kv[j];
    float e = __expf(fmaf(q, c.x, -m));
    s += e;
    t = fmaf(e, c.y, t);
  }
  if (jq) { ssum[jq - 1][il] = s; tsum[jq - 1][il] = t; }
  __syncthreads();
  if (jq == 0) {
    s += ssum[0][il] + ssum[1][il] + ssum[2][il];
    t += tsum[0][il] + tsum[1][il] + tsum[2][il];
    float o = t / s;
    xbuf[b * SS + i] += fmaf(o, owp[0], obp[0]);
  }
}

// ---------------- LDS-pipelined skinny GEMM ----------------
// A_q: [K/4][32][4]; W: [N][K] row-major; part: [ksplit][N/4][32][4]
// grid: (N/64, K/KC); block 256 (4 waves).
// Wave w owns rows e0+16w .. +15 (half h: 8 rows); lane&31 = batch b.
// Per 64k tile: W (16x64 f32/wave) staged via 4x global_load_lds_dwordx4,
// A (64k x 32b, 8KB/block) staged via 2x per wave. Double-buffered.
// Compute: A via ds_read_b128 (lane-distinct), W via half-wave-uniform
// broadcast ds_read_b128 (2-way = free).
__global__ __launch_bounds__(256) void k_gemm_lds(const float* __restrict__ Aq,
                                                  const float* __restrict__ W,
                                                  float* __restrict__ part,
                                                  int K, int N) {
  __shared__ __align__(16) float lw[2][4][16][64];  // 32 KB
  __shared__ __align__(16) float la[2][16][32][4];  // 16 KB
  int tid = threadIdx.x;
  int w = tid >> 6, lane = tid & 63, b = lane & 31, h = lane >> 5;
  int e0 = blockIdx.x << 6;
  int kc = blockIdx.y * KC;

  int srow = lane >> 4;          // staging row within 4-row group
  int scol = (lane & 15) << 2;   // staging k-offset

  float acc[8];
#pragma unroll
  for (int r = 0; r < 8; r++) acc[r] = 0.f;

  // ---- stage tile 0 ----
  {
    int kt = kc;
    const float* wbase = W + (size_t)(e0 + (w << 4)) * K + kt;
#pragma unroll
    for (int s = 0; s < 4; s++) {
      GLOAD_LDS16(wbase + (size_t)((s << 2) + srow) * K + scol, &lw[0][w][s << 2][0]);
    }
    const float* abase = Aq + (size_t)(kt >> 2) * 128;
#pragma unroll
    for (int s = 0; s < 2; s++) {
      GLOAD_LDS16(abase + (w << 9) + (s << 8) + (lane << 2),
                  &la[0][0][0][0] + (w << 9) + (s << 8));
    }
  }
  asm volatile("s_waitcnt vmcnt(0)" ::: "memory");
  __syncthreads();

  for (int t = 0; t < NT; t++) {
    // ---- prefetch tile t+1 into the other buffer ----
    if (t + 1 < NT) {
      int kt = kc + (t + 1) * KT;
      int nb = (t + 1) & 1;
      const float* wbase = W + (size_t)(e0 + (w << 4)) * K + kt;
#pragma unroll
      for (int s = 0; s < 4; s++) {
        GLOAD_LDS16(wbase + (size_t)((s << 2) + srow) * K + scol, &lw[nb][w][s << 2][0]);
      }
      const float* abase = Aq + (size_t)(kt >> 2) * 128;
#pragma unroll
      for (int s = 0; s < 2; s++) {
        GLOAD_LDS16(abase + (w << 9) + (s << 8) + (lane << 2),
                    &la[nb][0][0][0] + (w << 9) + (s << 8));
      }
    }
    // ---- compute tile t ----
    int cb = t & 1;
    const float(*wl)[64] = lw[cb][w];
    const float(*al)[32][4] = la[cb];
#pragma unroll
    for (int i = 0; i < 16; i++) {
      float4 a = *reinterpret_cast<const float4*>(&al[i][b][0]);
#pragma unroll
      for (int r = 0; r < 8; r++) {
        float4 wv = *reinterpret_cast<const float4*>(&wl[(h << 3) + r][i << 2]);
        acc[r] = fmaf(a.x, wv.x, acc[r]);
        acc[r] = fmaf(a.y, wv.y, acc[r]);
        acc[r] = fmaf(a.z, wv.z, acc[r]);
        acc[r] = fmaf(a.w, wv.w, acc[r]);
      }
    }
    asm volatile("s_waitcnt vmcnt(0)" ::: "memory");
    __syncthreads();
  }

  // ---- epilogue: q-layout partial store ----
  size_t pb = (size_t)blockIdx.y * ((size_t)N * 32);
  int ew = e0 + (w << 4) + (h << 3);
#pragma unroll
  for (int r = 0; r < 8; r++) {
    int e = ew + r;
    part[pb + (size_t)(e >> 2) * 128 + (b << 2) + (e & 3)] = acc[r];
  }
}

// ---------------- reduce gemm1 partials (ks=8): bias + leakyrelu -> h_q ----------------
__global__ __launch_bounds__(256) void k_reduce1(const float* __restrict__ part,
                                                 const float* __restrict__ b1,
                                                 float* __restrict__ hq) {
  int idx = blockIdx.x * 256 + threadIdx.x;
  float s = 0.f;
#pragma unroll
  for (int ks = 0; ks < 8; ks++) s += part[(size_t)ks * (BB * EE) + idx];
  int e = ((idx >> 7) << 2) | (idx & 3);
  s += b1[e];
  hq[idx] = s >= 0.f ? s : 0.5f * s;
}

// ---------------- reduce gemm2 partials (ks=24): bias + residual -> xbuf ----------------
__global__ __launch_bounds__(256) void k_reduce2(const float* __restrict__ part,
                                                 const float* __restrict__ b2,
                                                 float* __restrict__ xbuf) {
  __shared__ float ls[32][65];
  int s0 = blockIdx.x * 64;
  int base = (s0 >> 2) * 128;
  int t = threadIdx.x;
#pragma unroll
  for (int i = 0; i < 8; i++) {
    int idx = t + 256 * i;
    float s = 0.f;
#pragma unroll
    for (int ks = 0; ks < 24; ks++) s += part[(size_t)ks * (BB * SS) + base + idx];
    int sq = idx >> 7, bb = (idx >> 2) & 31, j = idx & 3;
    ls[bb][(sq << 2) | j] = s;
  }
  __syncthreads();
  int r = t >> 3, sc = (t & 7) * 8;
  float* xp = xbuf + (size_t)r * SS + s0 + sc;
  const float* bp = b2 + s0 + sc;
#pragma unroll
  for (int q = 0; q < 8; q++) xp[q] += ls[r][sc + q] + bp[q];
}

// ---------------- final renorm to original mean/var ----------------
__global__ __launch_bounds__(256) void k_final(const float* __restrict__ xbuf,
                                               const float* __restrict__ stats,
                                               float* __restrict__ out) {
  int b = blockIdx.x;
  const float* row = xbuf + b * SS;
  float s = 0.f, s2 = 0.f;
  for (int j = threadIdx.x; j < SS; j += 256) { float v = row[j]; s += v; s2 += v * v; }
  __shared__ float sm[8];
  __shared__ float smu, srs;
  for (int off = 32; off; off >>= 1) { s += __shfl_down(s, off); s2 += __shfl_down(s2, off); }
  int lane = threadIdx.x & 63, wid = threadIdx.x >> 6;
  if (lane == 0) { sm[wid] = s; sm[4 + wid] = s2; }
  __syncthreads();
  if (threadIdx.x == 0) {
    float ts = sm[0] + sm[1] + sm[2] + sm[3];
    float ts2 = sm[4] + sm[5] + sm[6] + sm[7];
    float mu = ts / SS;
    float var = (ts2 - SS * mu * mu) / (SS - 1);
    smu = mu;
    srs = rsqrtf(var + 2.220446049250313e-16f);
  }
  __syncthreads();
  float mu = smu, rs = srs;
  float scale = sqrtf(stats[BB + b] + 2.220446049250313e-16f);
  float mean0 = stats[b];
  for (int j = threadIdx.x; j < SS; j += 256) {
    out[b * SS + j] = (row[j] - mu) * rs * scale + mean0;
  }
}

extern "C" void kernel_launch(void* const* d_in, const int* in_sizes, int n_in,
                              void* d_out, int out_size, void* d_ws, size_t ws_size,
                              hipStream_t stream) {
  const float* x         = (const float*)d_in[0];
  const float* attn_ln_g = (const float*)d_in[1];
  const float* attn_ln_b = (const float*)d_in[2];
  const float* ipw       = (const float*)d_in[3];
  const float* ipb       = (const float*)d_in[4];
  const float* out_w     = (const float*)d_in[5];
  const float* out_b     = (const float*)d_in[6];
  const float* mlp_ln_g  = (const float*)d_in[7];
  const float* mlp_ln_b  = (const float*)d_in[8];
  const float* W1        = (const float*)d_in[9];
  const float* b1        = (const float*)d_in[10];
  const float* W2        = (const float*)d_in[11];
  const float* b2        = (const float*)d_in[12];

  float* ws    = (float*)d_ws;
  float* xbuf  = ws;                        // 65536
  float* uq    = xbuf + BB * SS;            // 65536
  float* hq    = uq + BB * SS;              // 196608
  float* part  = hq + BB * EE;              // 1572864 (8*196608 == 24*65536)
  float* stats = part + 8 * BB * EE;        // 64

  k_stats0<<<BB, 256, 0, stream>>>(x, xbuf, stats);

  for (int l = 0; l < 2; l++) {
    // ---- attention block ----
    k_layernorm<<<BB, 256, 0, stream>>>(xbuf, attn_ln_g + l * SS, attn_ln_b + l * SS, uq);
    k_attn<<<dim3(SS / 64, BB), 256, 0, stream>>>(uq, xbuf, ipw + l * 3, ipb + l * 3,
                                                  out_w + l, out_b + l);
    // ---- MLP block ----
    k_ln_q<<<BB, 256, 0, stream>>>(xbuf, mlp_ln_g + l * SS, mlp_ln_b + l * SS, uq);
    k_gemm_lds<<<dim3(EE / 64, SS / KC), 256, 0, stream>>>(uq, W1 + (size_t)l * EE * SS,
                                                           part, SS, EE);
    k_reduce1<<<BB * EE / 256, 256, 0, stream>>>(part, b1 + (size_t)l * EE, hq);
    k_gemm_lds<<<dim3(SS / 64, EE / KC), 256, 0, stream>>>(hq, W2 + (size_t)l * SS * EE,
                                                           part, EE, SS);
    k_reduce2<<<SS / 64, 256, 0, stream>>>(part, b2 + (size_t)l * SS, xbuf);
  }

  k_final<<<BB, 256, 0, stream>>>(xbuf, stats, (float*)d_out);
}